// Round 6
// baseline (117.573 us; speedup 1.0000x reference)
//
#include <hip/hip_runtime.h>

#define NNODES 8192
#define KZ 20
#define QB 16     // queries per block (one block == one 16-row gemm tile)
#define NTH 512
#define SCAP 192  // survivor cap per query; E[n]~45, bounds-guarded

// freqs[j] = 50^(-j/10)
static constexpr float FREQS[10] = {
  1.0f, 0.67624323f, 0.45730491f, 0.30924935f, 0.20912778f,
  0.14142136f, 0.09563524f, 0.06467268f, 0.04373443f, 0.02957512f};

// output offsets (floats)
#define O_XNE  0
#define O_POS  2621440
#define O_NBP  2646016
#define O_NBD  3137536
#define O_EDGE 6414336
#define O_FE   6578176

typedef __attribute__((ext_vector_type(8))) short bfrag;   // 8 bf16 (4 VGPRs)
typedef __attribute__((ext_vector_type(4))) float f32x4;   // MFMA C/D

static __device__ __forceinline__ unsigned short f2bf(float f) {
  unsigned int u = __float_as_uint(f);
  u += 0x7fffu + ((u >> 16) & 1u);
  return (unsigned short)(u >> 16);
}
// wave64 max-reduce via DPP (verified pattern), broadcast to all lanes.
static __device__ __forceinline__ float wave_max_f32(float v) {
  float t;
  t = __builtin_bit_cast(float, __builtin_amdgcn_update_dpp(__builtin_bit_cast(int, v), __builtin_bit_cast(int, v), 0x111, 0xF, 0xF, false)); v = fmaxf(v, t); // row_shr:1
  t = __builtin_bit_cast(float, __builtin_amdgcn_update_dpp(__builtin_bit_cast(int, v), __builtin_bit_cast(int, v), 0x112, 0xF, 0xF, false)); v = fmaxf(v, t); // row_shr:2
  t = __builtin_bit_cast(float, __builtin_amdgcn_update_dpp(__builtin_bit_cast(int, v), __builtin_bit_cast(int, v), 0x114, 0xF, 0xF, false)); v = fmaxf(v, t); // row_shr:4
  t = __builtin_bit_cast(float, __builtin_amdgcn_update_dpp(__builtin_bit_cast(int, v), __builtin_bit_cast(int, v), 0x118, 0xF, 0xF, false)); v = fmaxf(v, t); // row_shr:8
  t = __builtin_bit_cast(float, __builtin_amdgcn_update_dpp(__builtin_bit_cast(int, v), __builtin_bit_cast(int, v), 0x142, 0xF, 0xF, false)); v = fmaxf(v, t); // row_bcast:15
  t = __builtin_bit_cast(float, __builtin_amdgcn_update_dpp(__builtin_bit_cast(int, v), __builtin_bit_cast(int, v), 0x143, 0xF, 0xF, false)); v = fmaxf(v, t); // row_bcast:31
  return __builtin_bit_cast(float, __builtin_amdgcn_readlane(__builtin_bit_cast(int, v), 63));
}

// ---------------- prep + Wt bf16 cast (UNCHANGED) ----------------
__global__ __launch_bounds__(256) void k_pre(const float* __restrict__ affines,
                                             const int* __restrict__ prot_mask,
                                             const float* __restrict__ lit,
                                             const float* __restrict__ w,
                                             float* __restrict__ out,
                                             float4* __restrict__ pos4,
                                             float4* __restrict__ ncac4,
                                             unsigned short* __restrict__ wtb) {
  int t = blockIdx.x * 256 + threadIdx.x;  // < 131072
  {  // bf16 cast of ne_weight -> wtb[64][2048] (K-contiguous, zero pad)
    int o = t >> 11, k = t & 2047;
    wtb[t] = (k < 2000) ? f2bf(w[(size_t)o * 2000 + k]) : (unsigned short)0;
  }
  if (t < NNODES) {  // prep: positions, n2, ncac
    int n = t;
    const float4* af = (const float4*)affines + (size_t)n * 3;
    float4 a0 = af[0], a1 = af[1], a2 = af[2];  // rows of rot, .w = trans
    float tx = a0.w, ty = a1.w, tz = a2.w;
    float n2;
    {
#pragma clang fp contract(off)
      float xx = tx * tx;
      float yy = ty * ty;
      float zz = tz * tz;
      n2 = (xx + yy) + zz;
    }
    pos4[n] = make_float4(tx, ty, tz, n2);
    out[O_POS + n * 3 + 0] = tx;
    out[O_POS + n * 3 + 1] = ty;
    out[O_POS + n * 3 + 2] = tz;
    int aat = (prot_mask[n] != 0) ? 0 : 20;
    const float* lp = lit + aat * 9;
#pragma unroll
    for (int a = 0; a < 3; a++) {
      float l0 = lp[a * 3 + 0], l1 = lp[a * 3 + 1], l2 = lp[a * 3 + 2];
      float x = a0.x * l0 + a0.y * l1 + a0.z * l2 + tx;
      float y = a1.x * l0 + a1.y * l1 + a1.z * l2 + ty;
      float z = a2.x * l0 + a2.y * l1 + a2.z * l2 + tz;
      ncac4[n * 3 + a] = make_float4(x, y, z, 0.f);
    }
  }
}

// ---------------- FUSED KNN + gather + MFMA GEMM: QB=16, 512 threads ----------------
// d2 arithmetic bit-identical to all passing rounds:
//   dot = fmaf(z,pcz, fmaf(y,pcy, x*pcx)); d2 = fmaf(-2, dot, n2q + n2c)
// Pivot partitions: 64 groups of (8 threads x 16 cands) = 128 cands; pivot =
// 21st-smallest group min => all true top-20 <= pivot; exact u64
// (key<<13|idx) rank-select -> identical top-20 (order-independent).
// R6: (a) ballot-compacted job build (1 atomic per wave per query, offsets
// via lanemask -- job ORDER changes, output doesn't: rank-select is an exact
// sort on (d2,idx) keys); (b) rank->gather and gather->NBD barriers replaced
// by wave-local sync (nidx/dnbuf are wave-private); (c) NBD encode is
// wave-local (wave w encodes queries w,w+8; all 64 lanes active); (d) albs
// staging by col-PAIRS with uint4 LDS stores (16B-aligned, de-conflicted).
// GEMM tail: same f2bf(sinf) bits, same kq-quartered MFMA chains, same
// s0+s1+s2+s3 reduce order -> BIT-IDENTICAL output.
__global__ __launch_bounds__(512, 4) void k_knng(const float4* __restrict__ pos4,
                                                 const float* __restrict__ affines,
                                                 const float4* __restrict__ ncac4,
                                                 const float4* __restrict__ x4,
                                                 const unsigned short* __restrict__ wtb,
                                                 float* __restrict__ out) {
  __shared__ __align__(16) union {
    struct {
      float mca[QB][64];                   //  4 KB group minima
      unsigned long long surv[QB][SCAP];   // 24 KB
      unsigned short jobs[QB * NTH];       // 16 KB (max-sized: no guard needed)
      float dnbuf[QB][KZ];
      int nidx[QB][KZ];
      float pivots[QB];
      unsigned int cnt[QB];
      unsigned int njobs;
    } k;                                    // ~47.8 KB
    unsigned short albs[16][2056];          // 65.8 KB gemm A-tile
    float red[4][16][68];                   // 17.4 KB overlay (after albs dead)
  } u;
  __shared__ float distbuf[QB][100];        // 6.4 KB, persists knng->gemm
  int tid = threadIdx.x;
  int lane = tid & 63, w = tid >> 6;        // w in 0..7
  int qbase = blockIdx.x * QB;
  // x-copy prefetch: 16 rows x 64 float4 = 1024 items, 2 per thread.
  int xr0 = tid >> 6, xc0 = tid & 63;            // item tid
  int xr1 = (tid + 512) >> 6, xc1 = tid & 63;    // item tid+512
  float4 xv0 = x4[(size_t)(qbase + xr0) * 64 + xc0];
  float4 xv1 = x4[(size_t)(qbase + xr1) * 64 + xc1];
  // 16 query positions: wave-uniform
  float4 q0 = pos4[qbase + 0],  q1 = pos4[qbase + 1],  q2 = pos4[qbase + 2],  q3 = pos4[qbase + 3];
  float4 q4 = pos4[qbase + 4],  q5 = pos4[qbase + 5],  q6 = pos4[qbase + 6],  q7 = pos4[qbase + 7];
  float4 q8 = pos4[qbase + 8],  q9 = pos4[qbase + 9],  q10 = pos4[qbase + 10], q11 = pos4[qbase + 11];
  float4 q12 = pos4[qbase + 12], q13 = pos4[qbase + 13], q14 = pos4[qbase + 14], q15 = pos4[qbase + 15];
  const float4* pp = pos4 + tid;
  float l0, l1, l2, l3, l4, l5, l6, l7, l8, l9, l10, l11, l12, l13, l14, l15;
  l0 = l1 = l2 = l3 = l4 = l5 = l6 = l7 = l8 = l9 = l10 = l11 = l12 = l13 = l14 = l15 = __builtin_inff();
  {  // ---- pass 1: per-thread minima, 16 cands (stride 512) x 16 queries ----
#pragma clang fp contract(off)
#define DQ(i) { float d = fmaf(-2.0f, fmaf(q##i.z, pc.z, fmaf(q##i.y, pc.y, q##i.x * pc.x)), q##i.w + pc.w); l##i = fminf(l##i, d); }
#pragma unroll 2
    for (int s = 0; s < 16; s++) {
      float4 pc = pp[s << 9];
      DQ(0) DQ(1) DQ(2) DQ(3) DQ(4) DQ(5) DQ(6) DQ(7)
      DQ(8) DQ(9) DQ(10) DQ(11) DQ(12) DQ(13) DQ(14) DQ(15)
    }
#undef DQ
  }
  {  // ---- group-of-8 minima via shfl_xor -> mca ----
#define GM(i) { float v = l##i; v = fminf(v, __shfl_xor(v, 1)); v = fminf(v, __shfl_xor(v, 2)); v = fminf(v, __shfl_xor(v, 4)); if ((tid & 7) == 0) u.k.mca[i][tid >> 3] = v; }
    GM(0) GM(1) GM(2) GM(3) GM(4) GM(5) GM(6) GM(7)
    GM(8) GM(9) GM(10) GM(11) GM(12) GM(13) GM(14) GM(15)
#undef GM
  }
  if (tid == 0) u.k.njobs = 0u;
  __syncthreads();
  {  // ---- pivots: wave w handles queries w and w+8 ----
#pragma unroll
    for (int r = 0; r < 2; r++) {
      int q = w + 8 * r;
      float m = u.k.mca[q][lane];
      int c = 0;
#pragma unroll 8
      for (int j = 0; j < 64; j++) c += (u.k.mca[q][j] < m) ? 1 : 0;
      float elig = (c < KZ + 1) ? m : -__builtin_inff();
      float piv = wave_max_f32(elig);
      if (lane == 0) { u.k.pivots[q] = piv; u.k.cnt[q] = 0u; }
    }
  }
  __syncthreads();
  {  // ---- job build: ballot-compacted (1 atomic per wave per query) ----
    unsigned long long lmask = (lane == 63) ? ~0ull : ((1ull << (lane + 1)) - 1ull);
    unsigned long long ltmask = lmask >> 1;  // lanes strictly below me... (lane bits < lane)
    // note: ltmask = (1ull<<lane)-1 computed safely for lane=63
#define JB(i) { \
    bool p = (l##i <= u.k.pivots[i]); \
    unsigned long long mask = __ballot(p); \
    if (p) { \
      int leader = __ffsll((long long)mask) - 1; \
      unsigned int base = 0; \
      if (lane == leader) base = atomicAdd(&u.k.njobs, (unsigned int)__popcll(mask)); \
      base = (unsigned int)__shfl((int)base, leader); \
      unsigned int off = (unsigned int)__popcll(mask & ltmask); \
      u.k.jobs[base + off] = (unsigned short)((i << 9) | tid); \
    } }
    JB(0) JB(1) JB(2) JB(3) JB(4) JB(5) JB(6) JB(7)
    JB(8) JB(9) JB(10) JB(11) JB(12) JB(13) JB(14) JB(15)
#undef JB
  }
  __syncthreads();
  {  // ---- pass 2 (compacted): each job rescans its owner's 16 cands, 1 query ----
#pragma clang fp contract(off)
    unsigned int nj = u.k.njobs;
    for (unsigned int j = tid; j < nj; j += NTH) {
      int job = u.k.jobs[j];
      int q = job >> 9, owner = job & 511;
      int qidx = qbase + q;
      float4 qv = pos4[qidx];
      float pv = u.k.pivots[q];
      const float4* src = pos4 + owner;
#pragma unroll 8
      for (int s = 0; s < 16; s++) {
        float4 pc = src[s << 9];
        float dot = fmaf(qv.z, pc.z, fmaf(qv.y, pc.y, qv.x * pc.x));
        float d2 = fmaf(-2.0f, dot, qv.w + pc.w);
        int cc = (s << 9) + owner;
        if (d2 <= pv && cc != qidx) {
          unsigned int b = __float_as_uint(d2);
          unsigned int k = (b & 0x80000000u) ? ~b : (b | 0x80000000u);
          unsigned int ix = atomicAdd(&u.k.cnt[q], 1u);
          if (ix < SCAP)  // guard (never hit for this data)
            u.k.surv[q][ix] = ((unsigned long long)k << 13) | (unsigned int)cc;
        }
      }
    }
  }
  __syncthreads();
  {  // ---- exact rank-select: wave w handles queries w, w+8 ----
#pragma unroll
    for (int r = 0; r < 2; r++) {
      int q = w + 8 * r;
      unsigned int n = u.k.cnt[q]; if (n > SCAP) n = SCAP;
      int qi = qbase + q;
      for (unsigned int j = lane; j < n; j += 64) {
        unsigned long long my = u.k.surv[q][j];
        int rank = 0;
        unsigned int t = 0;
        for (; t + 4 <= n; t += 4) {
          unsigned long long s0 = u.k.surv[q][t + 0];
          unsigned long long s1 = u.k.surv[q][t + 1];
          unsigned long long s2 = u.k.surv[q][t + 2];
          unsigned long long s3 = u.k.surv[q][t + 3];
          rank += ((s0 < my) ? 1 : 0) + ((s1 < my) ? 1 : 0) +
                  ((s2 < my) ? 1 : 0) + ((s3 < my) ? 1 : 0);
        }
        for (; t < n; t++) rank += (u.k.surv[q][t] < my) ? 1 : 0;
        if (rank < KZ) {
          int idx = (int)(my & 0x1FFFull);
          u.k.nidx[q][rank] = idx;
          float fi = (float)idx;
          out[O_EDGE + qi * KZ + rank] = fi;                     // edge_index
          out[O_FE + qi * KZ + rank] = fi;                       // full_edge row0
          out[O_FE + NNODES * KZ + qi * KZ + rank] = (float)qi;  // full_edge row1
        }
      }
    }
  }
  // NO block barrier: nidx[q] / dnbuf[q] are wave-private for q = w, w+8.
  // ---- x-copy store (prefetched at entry; fire-and-forget) ----
  ((float4*)out)[(size_t)(qbase + xr0) * 80 + xc0] = xv0;
  ((float4*)out)[(size_t)(qbase + xr1) * 80 + xc1] = xv1;
  __builtin_amdgcn_s_waitcnt(0xC07F);  // lgkmcnt(0): my wave's nidx writes visible
  __builtin_amdgcn_wave_barrier();
  {  // ---- gather tail: wave w serves queries w, w+8 on lanes 0..19 ----
#pragma unroll
    for (int r = 0; r < 2; r++) {
      int q = w + 8 * r;
      int qi = qbase + q;
      if (lane < KZ) {
        const float4* af = (const float4*)affines + (size_t)qi * 3;
        float4 a0 = af[0], a1 = af[1], a2 = af[2];
        float tx = a0.w, ty = a1.w, tz = a2.w;
        int idx = u.k.nidx[q][lane];
        float4 p = pos4[idx];
        float bx = p.x - tx, by = p.y - ty, bz = p.z - tz;
        // einsum('nji,nkj->nki'): v_i = sum_j rot[j][i]*b_j (rot^T)
        float vx = a0.x * bx + a1.x * by + a2.x * bz;
        float vy = a0.y * bx + a1.y * by + a2.y * bz;
        float vz = a0.z * bx + a1.z * by + a2.z * bz;
        out[O_NBP + qi * 60 + lane * 3 + 0] = vx;
        out[O_NBP + qi * 60 + lane * 3 + 1] = vy;
        out[O_NBP + qi * 60 + lane * 3 + 2] = vz;
        float dn = sqrtf(vx * vx + vy * vy + vz * vz);
        u.k.dnbuf[q][lane] = dn;
        float4 cn = ncac4[(size_t)qi * 3 + 0];   // n_pos
        float4 ca = ncac4[(size_t)qi * 3 + 1];   // ca_pos
        float4 cc = ncac4[(size_t)qi * 3 + 2];   // c_pos
        float4 nb0 = ncac4[(size_t)idx * 3 + 0];
        float4 nb1 = ncac4[(size_t)idx * 3 + 1];
        float4 nb2 = ncac4[(size_t)idx * 3 + 2];
        auto dist = [](float4 a, float4 b) {
          float dx = a.x - b.x, dy = a.y - b.y, dz = a.z - b.z;
          return sqrtf(dx * dx + dy * dy + dz * dz);
        };
        distbuf[q][lane * 3 + 0] = dist(nb0, ca);
        distbuf[q][lane * 3 + 1] = dist(nb1, ca);
        distbuf[q][lane * 3 + 2] = dist(nb2, ca);
        distbuf[q][60 + lane] = dist(nb2, cn);  // n_to_c
        distbuf[q][80 + lane] = dist(nb0, cc);  // c_to_n
      }
    }
  }
  __builtin_amdgcn_s_waitcnt(0xC07F);  // lgkmcnt(0): my wave's dnbuf writes visible
  __builtin_amdgcn_wave_barrier();
  {  // ---- NBD sinusoidal encode: wave-local, 2 queries x 200 items over 64 lanes ----
#pragma unroll
    for (int r = 0; r < 2; r++) {
      int q = w + 8 * r;
      int base0 = O_NBD + (qbase + q) * 400;
      for (int uu = lane; uu < KZ * 10; uu += 64) {
        int nb = uu / 10, j = uu - nb * 10;
        float a = u.k.dnbuf[q][nb] * FREQS[j];
        out[base0 + nb * 20 + j] = __sinf(a);
        out[base0 + nb * 20 + 10 + j] = __cosf(a);
      }
    }
  }
  __syncthreads();  // all distbuf writes visible; k-region dead; albs may clobber union
  // ================= GEMM tail (bit-identical) =================
  {  // ---- stage A-tile: 800 (row,colpair) items; 5x uint4 LDS stores each ----
    for (int uu = tid; uu < 800; uu += NTH) {
      int row = uu / 50, cp = uu - row * 50;  // cols 2cp, 2cp+1
      float dA = distbuf[row][2 * cp];
      float dB = distbuf[row][2 * cp + 1];
      unsigned int dw[20];
#pragma unroll
      for (int j = 0; j < 10; j++) {
        float aA = dA * FREQS[j];
        float aB = dB * FREQS[j];
        unsigned short sA = f2bf(__sinf(aA)), cA = f2bf(__cosf(aA));
        unsigned short sB = f2bf(__sinf(aB)), cB = f2bf(__cosf(aB));
        // layout: [sinA(0..9) cosA(0..9) sinB(0..9) cosB(0..9)] as shorts
        // dword i packs shorts 2i,2i+1
        ((unsigned short*)dw)[j] = sA;
        ((unsigned short*)dw)[10 + j] = cA;
        ((unsigned short*)dw)[20 + j] = sB;
        ((unsigned short*)dw)[30 + j] = cB;
      }
      uint4* dst = (uint4*)&u.albs[row][cp * 40];  // 80B, 16B-aligned (4112*row+80*cp)
#pragma unroll
      for (int v = 0; v < 5; v++)
        dst[v] = ((const uint4*)dw)[v];
    }
    // zero K-pad cols [2000,2048): 6 uint4 per row x 16 rows
    for (int uu = tid; uu < 16 * 6; uu += NTH) {
      int row = uu / 6, v = uu - row * 6;
      ((uint4*)&u.albs[row][2000])[v] = make_uint4(0u, 0u, 0u, 0u);
    }
  }
  __syncthreads();
  int m0 = qbase;
  int kq = w & 3, nh = w >> 2;        // k-quarter, n-half
  int am = lane & 15, ak = (lane >> 4) * 8;
  const unsigned short* arow = &u.albs[am][kq * 512 + ak];
  const unsigned short* brow = wtb + (size_t)(am + nh * 32) * 2048 + kq * 512 + ak;
  f32x4 acc0 = {0.f, 0.f, 0.f, 0.f}, acc1 = acc0;
#pragma unroll 8
  for (int ks = 0; ks < 16; ks++) {
    bfrag a = *(const bfrag*)(arow + ks * 32);
    bfrag b0 = *(const bfrag*)(brow + ks * 32);
    bfrag b1 = *(const bfrag*)(brow + 16 * 2048 + ks * 32);
    acc0 = __builtin_amdgcn_mfma_f32_16x16x32_bf16(a, b0, acc0, 0, 0, 0);
    acc1 = __builtin_amdgcn_mfma_f32_16x16x32_bf16(a, b1, acc1, 0, 0, 0);
  }
  __syncthreads();  // all albs reads done; red may overlay
  {  // write partials: row=(lane>>4)*4+r_, col=lane&15 (+16 per tile, +32 per nh)
    int rm = (lane >> 4) * 4, cn = lane & 15;
#pragma unroll
    for (int r_ = 0; r_ < 4; r_++) {
      u.red[kq][rm + r_][nh * 32 + cn]      = acc0[r_];
      u.red[kq][rm + r_][nh * 32 + 16 + cn] = acc1[r_];
    }
  }
  __syncthreads();
  if (tid < 256) {
    // reduce 4 partials; 256 threads x one float4 = 16 rows x 64 cols
    int m = tid >> 4, n = (tid & 15) * 4;
    float4 s0 = *(const float4*)&u.red[0][m][n];
    float4 s1 = *(const float4*)&u.red[1][m][n];
    float4 s2 = *(const float4*)&u.red[2][m][n];
    float4 s3 = *(const float4*)&u.red[3][m][n];
    float4 s = make_float4(s0.x + s1.x + s2.x + s3.x, s0.y + s1.y + s2.y + s3.y,
                           s0.z + s1.z + s2.z + s3.z, s0.w + s1.w + s2.w + s3.w);
    *(float4*)&out[(size_t)(m0 + m) * 320 + 256 + n] = s;
  }
}

extern "C" void kernel_launch(void* const* d_in, const int* in_sizes, int n_in,
                              void* d_out, int out_size, void* d_ws, size_t ws_size,
                              hipStream_t stream) {
  const float* x = (const float*)d_in[0];
  const float* affines = (const float*)d_in[1];
  const float* ne_w = (const float*)d_in[2];
  const float* lit = (const float*)d_in[3];
  const int* mask = (const int*)d_in[4];
  float* out = (float*)d_out;
  char* ws = (char*)d_ws;
  // ws layout (bytes)
  float4* pos4 = (float4*)(ws + 0);                   //  8192*16   = 131072
  float4* ncac4 = (float4*)(ws + 131072);             //  8192*48   -> 524288
  unsigned short* wtb = (unsigned short*)(ws + 524288);   // 64*2048*2 -> 786432

  k_pre<<<512, 256, 0, stream>>>(affines, mask, lit, ne_w, out, pos4, ncac4, wtb);
  k_knng<<<NNODES / QB, NTH, 0, stream>>>(pos4, affines, ncac4, (const float4*)x, wtb, out);
}

// Round 8
// 116.331 us; speedup vs baseline: 1.0107x; 1.0107x over previous
//
#include <hip/hip_runtime.h>

#define NNODES 8192
#define KZ 20
#define QB 16     // queries per block == one 16-row gemm tile
#define NTH 1024  // R8: 512 blocks x 1024 thr = 524288 = 100% device thread capacity
#define SCAP 192  // survivor cap per query; E[n]~45, bounds-guarded
#define JCAP 4096 // job cap; bound: jobs <= QB*(SCAP+1) ~ 3.1K < 4096 (guarded)

// freqs[j] = 50^(-j/10)
static constexpr float FREQS[10] = {
  1.0f, 0.67624323f, 0.45730491f, 0.30924935f, 0.20912778f,
  0.14142136f, 0.09563524f, 0.06467268f, 0.04373443f, 0.02957512f};

// output offsets (floats)
#define O_XNE  0
#define O_POS  2621440
#define O_NBP  2646016
#define O_NBD  3137536
#define O_EDGE 6414336
#define O_FE   6578176

typedef __attribute__((ext_vector_type(8))) short bfrag;   // 8 bf16 (4 VGPRs)
typedef __attribute__((ext_vector_type(4))) float f32x4;   // MFMA C/D

static __device__ __forceinline__ unsigned short f2bf(float f) {
  unsigned int u = __float_as_uint(f);
  u += 0x7fffu + ((u >> 16) & 1u);
  return (unsigned short)(u >> 16);
}
// wave64 max-reduce via DPP, broadcast to all lanes.
static __device__ __forceinline__ float wave_max_f32(float v) {
  float t;
  t = __builtin_bit_cast(float, __builtin_amdgcn_update_dpp(__builtin_bit_cast(int, v), __builtin_bit_cast(int, v), 0x111, 0xF, 0xF, false)); v = fmaxf(v, t); // row_shr:1
  t = __builtin_bit_cast(float, __builtin_amdgcn_update_dpp(__builtin_bit_cast(int, v), __builtin_bit_cast(int, v), 0x112, 0xF, 0xF, false)); v = fmaxf(v, t); // row_shr:2
  t = __builtin_bit_cast(float, __builtin_amdgcn_update_dpp(__builtin_bit_cast(int, v), __builtin_bit_cast(int, v), 0x114, 0xF, 0xF, false)); v = fmaxf(v, t); // row_shr:4
  t = __builtin_bit_cast(float, __builtin_amdgcn_update_dpp(__builtin_bit_cast(int, v), __builtin_bit_cast(int, v), 0x118, 0xF, 0xF, false)); v = fmaxf(v, t); // row_shr:8
  t = __builtin_bit_cast(float, __builtin_amdgcn_update_dpp(__builtin_bit_cast(int, v), __builtin_bit_cast(int, v), 0x142, 0xF, 0xF, false)); v = fmaxf(v, t); // row_bcast:15
  t = __builtin_bit_cast(float, __builtin_amdgcn_update_dpp(__builtin_bit_cast(int, v), __builtin_bit_cast(int, v), 0x143, 0xF, 0xF, false)); v = fmaxf(v, t); // row_bcast:31
  return __builtin_bit_cast(float, __builtin_amdgcn_readlane(__builtin_bit_cast(int, v), 63));
}

// ---------------- prep + Wt bf16 cast (UNCHANGED from R5/R6; proven) ----------------
__global__ __launch_bounds__(256) void k_pre(const float* __restrict__ affines,
                                             const int* __restrict__ prot_mask,
                                             const float* __restrict__ lit,
                                             const float* __restrict__ w,
                                             float* __restrict__ out,
                                             float4* __restrict__ pos4,
                                             float4* __restrict__ ncac4,
                                             unsigned short* __restrict__ wtb) {
  int t = blockIdx.x * 256 + threadIdx.x;  // < 131072
  {  // bf16 cast of ne_weight -> wtb[64][2048] (K-contiguous, zero pad)
    int o = t >> 11, k = t & 2047;
    wtb[t] = (k < 2000) ? f2bf(w[(size_t)o * 2000 + k]) : (unsigned short)0;
  }
  if (t < NNODES) {  // prep: positions, n2, ncac
    int n = t;
    const float4* af = (const float4*)affines + (size_t)n * 3;
    float4 a0 = af[0], a1 = af[1], a2 = af[2];  // rows of rot, .w = trans
    float tx = a0.w, ty = a1.w, tz = a2.w;
    float n2;
    {
#pragma clang fp contract(off)
      float xx = tx * tx;
      float yy = ty * ty;
      float zz = tz * tz;
      n2 = (xx + yy) + zz;
    }
    pos4[n] = make_float4(tx, ty, tz, n2);
    out[O_POS + n * 3 + 0] = tx;
    out[O_POS + n * 3 + 1] = ty;
    out[O_POS + n * 3 + 2] = tz;
    int aat = (prot_mask[n] != 0) ? 0 : 20;
    const float* lp = lit + aat * 9;
#pragma unroll
    for (int a = 0; a < 3; a++) {
      float l0 = lp[a * 3 + 0], l1 = lp[a * 3 + 1], l2 = lp[a * 3 + 2];
      float x = a0.x * l0 + a0.y * l1 + a0.z * l2 + tx;
      float y = a1.x * l0 + a1.y * l1 + a1.z * l2 + ty;
      float z = a2.x * l0 + a2.y * l1 + a2.z * l2 + tz;
      ncac4[n * 3 + a] = make_float4(x, y, z, 0.f);
    }
  }
}

// ---------------- FUSED KNN + gather + MFMA GEMM: QB=16, 1024 threads ----------------
// R8: NTH=1024 (16 waves); wave w <-> query w everywhere (single round).
// Pass 1: 8 cands/thread (stride 1024) x 16 queries. Partitions: 16 threads x
// 8 cands = 128 cands (SAME partition size as all passing rounds); pivot =
// 21st-smallest of 64 partition minima => >=21 elements <= pivot => >=20
// non-self => exact top-20 after u64 (key<<13|idx) rank-select.
// d2 bit-identical: dot = fmaf(z,pcz, fmaf(y,pcy, x*pcx)); d2 = fmaf(-2,dot,n2q+n2c)
// GEMM: 16 waves = 4 K-quarters x 4 N-quarters; each wave one intact 16-step
// MFMA chain == exactly the chains of the 8-wave version (acc0/acc1 split into
// two waves); same red[] slots, same s0+s1+s2+s3 reduce -> BIT-IDENTICAL.
__global__ __launch_bounds__(1024, 8) void k_knng(const float4* __restrict__ pos4,
                                                  const float* __restrict__ affines,
                                                  const float4* __restrict__ ncac4,
                                                  const float4* __restrict__ x4,
                                                  const unsigned short* __restrict__ wtb,
                                                  float* __restrict__ out) {
  __shared__ __align__(16) union {
    struct {
      float mca[QB][64];                   //  4 KB group minima
      unsigned long long surv[QB][SCAP];   // 24 KB
      unsigned short jobs[JCAP];           //  8 KB (guarded)
      float dnbuf[QB][KZ];
      int nidx[QB][KZ];
      float pivots[QB];
      unsigned int cnt[QB];
      unsigned int njobs;
    } k;                                    // ~39.6 KB
    unsigned short albs[16][2056];          // 65.8 KB gemm A-tile
    float red[4][16][68];                   // 17.4 KB overlay (after albs dead)
  } u;
  __shared__ float distbuf[QB][100];        // 6.4 KB, persists knng->gemm
  int tid = threadIdx.x;
  int lane = tid & 63, w = tid >> 6;        // w in 0..15
  int qbase = blockIdx.x * QB;
  // x-copy prefetch: 16 rows x 64 float4 = 1024 items, 1 per thread.
  int xr = tid >> 6, xc = tid & 63;
  float4 xv = x4[(size_t)(qbase + xr) * 64 + xc];
  // 16 query positions: block-uniform -> scalar regs
  float4 q0 = pos4[qbase + 0],  q1 = pos4[qbase + 1],  q2 = pos4[qbase + 2],  q3 = pos4[qbase + 3];
  float4 q4 = pos4[qbase + 4],  q5 = pos4[qbase + 5],  q6 = pos4[qbase + 6],  q7 = pos4[qbase + 7];
  float4 q8 = pos4[qbase + 8],  q9 = pos4[qbase + 9],  q10 = pos4[qbase + 10], q11 = pos4[qbase + 11];
  float4 q12 = pos4[qbase + 12], q13 = pos4[qbase + 13], q14 = pos4[qbase + 14], q15 = pos4[qbase + 15];
  const float4* pp = pos4 + tid;
  float l0, l1, l2, l3, l4, l5, l6, l7, l8, l9, l10, l11, l12, l13, l14, l15;
  l0 = l1 = l2 = l3 = l4 = l5 = l6 = l7 = l8 = l9 = l10 = l11 = l12 = l13 = l14 = l15 = __builtin_inff();
  {  // ---- pass 1: per-thread minima, 8 cands (stride 1024) x 16 queries ----
#pragma clang fp contract(off)
#define DQ(i) { float d = fmaf(-2.0f, fmaf(q##i.z, pc.z, fmaf(q##i.y, pc.y, q##i.x * pc.x)), q##i.w + pc.w); l##i = fminf(l##i, d); }
#pragma unroll 2
    for (int s = 0; s < 8; s++) {
      float4 pc = pp[s << 10];
      DQ(0) DQ(1) DQ(2) DQ(3) DQ(4) DQ(5) DQ(6) DQ(7)
      DQ(8) DQ(9) DQ(10) DQ(11) DQ(12) DQ(13) DQ(14) DQ(15)
    }
#undef DQ
  }
  {  // ---- group-of-16 minima via shfl_xor(1,2,4,8) -> mca[q][tid>>4] ----
#define GM(i) { float v = l##i; v = fminf(v, __shfl_xor(v, 1)); v = fminf(v, __shfl_xor(v, 2)); v = fminf(v, __shfl_xor(v, 4)); v = fminf(v, __shfl_xor(v, 8)); if ((tid & 15) == 0) u.k.mca[i][tid >> 4] = v; }
    GM(0) GM(1) GM(2) GM(3) GM(4) GM(5) GM(6) GM(7)
    GM(8) GM(9) GM(10) GM(11) GM(12) GM(13) GM(14) GM(15)
#undef GM
  }
  if (tid == 0) u.k.njobs = 0u;
  __syncthreads();
  {  // ---- pivot: wave w handles query w ----
    float m = u.k.mca[w][lane];
    int c = 0;
#pragma unroll 8
    for (int j = 0; j < 64; j++) c += (u.k.mca[w][j] < m) ? 1 : 0;
    float elig = (c < KZ + 1) ? m : -__builtin_inff();
    float piv = wave_max_f32(elig);
    if (lane == 0) { u.k.pivots[w] = piv; u.k.cnt[w] = 0u; }
  }
  __syncthreads();
  {  // ---- job build: ballot-compacted (1 atomic per wave per query) ----
    unsigned long long lmask = (lane == 63) ? ~0ull : ((1ull << (lane + 1)) - 1ull);
    unsigned long long ltmask = lmask >> 1;  // lanes strictly below me
#define JB(i) { \
    bool p = (l##i <= u.k.pivots[i]); \
    unsigned long long mask = __ballot(p); \
    if (p) { \
      int leader = __ffsll((long long)mask) - 1; \
      unsigned int base = 0; \
      if (lane == leader) base = atomicAdd(&u.k.njobs, (unsigned int)__popcll(mask)); \
      base = (unsigned int)__shfl((int)base, leader); \
      unsigned int ix = base + (unsigned int)__popcll(mask & ltmask); \
      if (ix < JCAP) u.k.jobs[ix] = (unsigned short)((i << 10) | tid); \
    } }
    JB(0) JB(1) JB(2) JB(3) JB(4) JB(5) JB(6) JB(7)
    JB(8) JB(9) JB(10) JB(11) JB(12) JB(13) JB(14) JB(15)
#undef JB
  }
  __syncthreads();
  {  // ---- pass 2 (compacted): each job rescans its owner's 8 cands, 1 query ----
#pragma clang fp contract(off)
    unsigned int nj = u.k.njobs; if (nj > JCAP) nj = JCAP;
    for (unsigned int j = tid; j < nj; j += NTH) {
      int job = u.k.jobs[j];
      int q = job >> 10, owner = job & 1023;
      int qidx = qbase + q;
      float4 qv = pos4[qidx];
      float pv = u.k.pivots[q];
      const float4* src = pos4 + owner;
#pragma unroll
      for (int s = 0; s < 8; s++) {
        float4 pc = src[s << 10];
        float dot = fmaf(qv.z, pc.z, fmaf(qv.y, pc.y, qv.x * pc.x));
        float d2 = fmaf(-2.0f, dot, qv.w + pc.w);
        int cc = (s << 10) + owner;
        if (d2 <= pv && cc != qidx) {
          unsigned int b = __float_as_uint(d2);
          unsigned int k = (b & 0x80000000u) ? ~b : (b | 0x80000000u);
          unsigned int ix = atomicAdd(&u.k.cnt[q], 1u);
          if (ix < SCAP)  // guard (never hit for this data)
            u.k.surv[q][ix] = ((unsigned long long)k << 13) | (unsigned int)cc;
        }
      }
    }
  }
  __syncthreads();
  {  // ---- exact rank-select: wave w handles query w ----
    unsigned int n = u.k.cnt[w]; if (n > SCAP) n = SCAP;
    int qi = qbase + w;
    for (unsigned int j = lane; j < n; j += 64) {
      unsigned long long my = u.k.surv[w][j];
      int rank = 0;
      unsigned int t = 0;
      for (; t + 4 <= n; t += 4) {
        unsigned long long s0 = u.k.surv[w][t + 0];
        unsigned long long s1 = u.k.surv[w][t + 1];
        unsigned long long s2 = u.k.surv[w][t + 2];
        unsigned long long s3 = u.k.surv[w][t + 3];
        rank += ((s0 < my) ? 1 : 0) + ((s1 < my) ? 1 : 0) +
                ((s2 < my) ? 1 : 0) + ((s3 < my) ? 1 : 0);
      }
      for (; t < n; t++) rank += (u.k.surv[w][t] < my) ? 1 : 0;
      if (rank < KZ) {
        int idx = (int)(my & 0x1FFFull);
        u.k.nidx[w][rank] = idx;
        float fi = (float)idx;
        out[O_EDGE + qi * KZ + rank] = fi;                     // edge_index
        out[O_FE + qi * KZ + rank] = fi;                       // full_edge row0
        out[O_FE + NNODES * KZ + qi * KZ + rank] = (float)qi;  // full_edge row1
      }
    }
  }
  // NO block barrier: nidx[w]/dnbuf[w] are wave-private.
  ((float4*)out)[(size_t)(qbase + xr) * 80 + xc] = xv;  // x-copy store
  __builtin_amdgcn_s_waitcnt(0xC07F);  // lgkmcnt(0): my wave's nidx writes visible
  __builtin_amdgcn_wave_barrier();
  {  // ---- gather tail: wave w serves query w on lanes 0..19 ----
    int qi = qbase + w;
    if (lane < KZ) {
      const float4* af = (const float4*)affines + (size_t)qi * 3;
      float4 a0 = af[0], a1 = af[1], a2 = af[2];
      float tx = a0.w, ty = a1.w, tz = a2.w;
      int idx = u.k.nidx[w][lane];
      float4 p = pos4[idx];
      float bx = p.x - tx, by = p.y - ty, bz = p.z - tz;
      // einsum('nji,nkj->nki'): v_i = sum_j rot[j][i]*b_j (rot^T)
      float vx = a0.x * bx + a1.x * by + a2.x * bz;
      float vy = a0.y * bx + a1.y * by + a2.y * bz;
      float vz = a0.z * bx + a1.z * by + a2.z * bz;
      out[O_NBP + qi * 60 + lane * 3 + 0] = vx;
      out[O_NBP + qi * 60 + lane * 3 + 1] = vy;
      out[O_NBP + qi * 60 + lane * 3 + 2] = vz;
      float dn = sqrtf(vx * vx + vy * vy + vz * vz);
      u.k.dnbuf[w][lane] = dn;
      float4 cn = ncac4[(size_t)qi * 3 + 0];   // n_pos
      float4 ca = ncac4[(size_t)qi * 3 + 1];   // ca_pos
      float4 cc = ncac4[(size_t)qi * 3 + 2];   // c_pos
      float4 nb0 = ncac4[(size_t)idx * 3 + 0];
      float4 nb1 = ncac4[(size_t)idx * 3 + 1];
      float4 nb2 = ncac4[(size_t)idx * 3 + 2];
      auto dist = [](float4 a, float4 b) {
        float dx = a.x - b.x, dy = a.y - b.y, dz = a.z - b.z;
        return sqrtf(dx * dx + dy * dy + dz * dz);
      };
      distbuf[w][lane * 3 + 0] = dist(nb0, ca);
      distbuf[w][lane * 3 + 1] = dist(nb1, ca);
      distbuf[w][lane * 3 + 2] = dist(nb2, ca);
      distbuf[w][60 + lane] = dist(nb2, cn);  // n_to_c
      distbuf[w][80 + lane] = dist(nb0, cc);  // c_to_n
    }
  }
  __builtin_amdgcn_s_waitcnt(0xC07F);  // lgkmcnt(0): my wave's dnbuf writes visible
  __builtin_amdgcn_wave_barrier();
  {  // ---- NBD sinusoidal encode: wave-local, query w, 200 items over 64 lanes ----
    int base0 = O_NBD + (qbase + w) * 400;
    for (int uu = lane; uu < KZ * 10; uu += 64) {
      int nb = uu / 10, j = uu - nb * 10;
      float a = u.k.dnbuf[w][nb] * FREQS[j];
      out[base0 + nb * 20 + j] = __sinf(a);
      out[base0 + nb * 20 + 10 + j] = __cosf(a);
    }
  }
  __syncthreads();  // all distbuf writes visible; k-region dead; albs may clobber union
  // ================= GEMM tail (bit-identical) =================
  {  // ---- stage A-tile: 800 (row,colpair) items; 5x uint4 LDS stores each ----
    for (int uu = tid; uu < 800; uu += NTH) {
      int row = uu / 50, cp = uu - row * 50;  // cols 2cp, 2cp+1
      float dA = distbuf[row][2 * cp];
      float dB = distbuf[row][2 * cp + 1];
      unsigned int dw[20];
#pragma unroll
      for (int j = 0; j < 10; j++) {
        float aA = dA * FREQS[j];
        float aB = dB * FREQS[j];
        unsigned short sA = f2bf(__sinf(aA)), cA = f2bf(__cosf(aA));
        unsigned short sB = f2bf(__sinf(aB)), cB = f2bf(__cosf(aB));
        ((unsigned short*)dw)[j] = sA;
        ((unsigned short*)dw)[10 + j] = cA;
        ((unsigned short*)dw)[20 + j] = sB;
        ((unsigned short*)dw)[30 + j] = cB;
      }
      uint4* dst = (uint4*)&u.albs[row][cp * 40];  // 80B, 16B-aligned
#pragma unroll
      for (int v = 0; v < 5; v++)
        dst[v] = ((const uint4*)dw)[v];
    }
    // zero K-pad cols [2000,2048): 6 uint4 per row x 16 rows
    for (int uu = tid; uu < 16 * 6; uu += NTH) {
      int row = uu / 6, v = uu - row * 6;
      ((uint4*)&u.albs[row][2000])[v] = make_uint4(0u, 0u, 0u, 0u);
    }
  }
  __syncthreads();
  int m0 = qbase;
  int kq = w & 3, nq = w >> 2;        // k-quarter, n-quarter (16 waves)
  int am = lane & 15, ak = (lane >> 4) * 8;
  const unsigned short* arow = &u.albs[am][kq * 512 + ak];
  const unsigned short* brow = wtb + (size_t)(am + nq * 16) * 2048 + kq * 512 + ak;
  f32x4 acc = {0.f, 0.f, 0.f, 0.f};
#pragma unroll 8
  for (int ks = 0; ks < 16; ks++) {
    bfrag a = *(const bfrag*)(arow + ks * 32);
    bfrag b = *(const bfrag*)(brow + ks * 32);
    acc = __builtin_amdgcn_mfma_f32_16x16x32_bf16(a, b, acc, 0, 0, 0);
  }
  __syncthreads();  // all albs reads done; red may overlay
  {  // write partials: row=(lane>>4)*4+r_, col=lane&15 (+16 per n-quarter)
    int rm = (lane >> 4) * 4, cn = lane & 15;
#pragma unroll
    for (int r_ = 0; r_ < 4; r_++)
      u.red[kq][rm + r_][nq * 16 + cn] = acc[r_];
  }
  __syncthreads();
  if (tid < 256) {
    // reduce 4 partials; 256 threads x one float4 = 16 rows x 64 cols
    int m = tid >> 4, n = (tid & 15) * 4;
    float4 s0 = *(const float4*)&u.red[0][m][n];
    float4 s1 = *(const float4*)&u.red[1][m][n];
    float4 s2 = *(const float4*)&u.red[2][m][n];
    float4 s3 = *(const float4*)&u.red[3][m][n];
    float4 s = make_float4(s0.x + s1.x + s2.x + s3.x, s0.y + s1.y + s2.y + s3.y,
                           s0.z + s1.z + s2.z + s3.z, s0.w + s1.w + s2.w + s3.w);
    *(float4*)&out[(size_t)(m0 + m) * 320 + 256 + n] = s;
  }
}

extern "C" void kernel_launch(void* const* d_in, const int* in_sizes, int n_in,
                              void* d_out, int out_size, void* d_ws, size_t ws_size,
                              hipStream_t stream) {
  const float* x = (const float*)d_in[0];
  const float* affines = (const float*)d_in[1];
  const float* ne_w = (const float*)d_in[2];
  const float* lit = (const float*)d_in[3];
  const int* mask = (const int*)d_in[4];
  float* out = (float*)d_out;
  char* ws = (char*)d_ws;
  // ws layout (bytes)
  float4* pos4 = (float4*)(ws + 0);                   //  8192*16   = 131072
  float4* ncac4 = (float4*)(ws + 131072);             //  8192*48   -> 524288
  unsigned short* wtb = (unsigned short*)(ws + 524288);   // 64*2048*2 -> 786432

  k_pre<<<512, 256, 0, stream>>>(affines, mask, lit, ne_w, out, pos4, ncac4, wtb);
  k_knng<<<NNODES / QB, NTH, 0, stream>>>(pos4, affines, ncac4, (const float4*)x, wtb, out);
}

// Round 10
// 115.561 us; speedup vs baseline: 1.0174x; 1.0067x over previous
//
#include <hip/hip_runtime.h>

#define NNODES 8192
#define KZ 20
#define QB 16     // queries per block == one 16-row gemm tile
#define NTH 1024  // 512 blocks x 1024 thr = 100% device thread capacity
#define SCAP 192  // survivor cap per query; E[n]~45, bounds-guarded
#define JCAP 4096 // job cap; bound: jobs <= QB*(SCAP+1) ~ 3.1K < 4096 (guarded)

// freqs[j] = 50^(-j/10)
static constexpr float FREQS[10] = {
  1.0f, 0.67624323f, 0.45730491f, 0.30924935f, 0.20912778f,
  0.14142136f, 0.09563524f, 0.06467268f, 0.04373443f, 0.02957512f};

// output offsets (floats)
#define O_XNE  0
#define O_POS  2621440
#define O_NBP  2646016
#define O_NBD  3137536
#define O_EDGE 6414336
#define O_FE   6578176

typedef __attribute__((ext_vector_type(8))) short bfrag;   // 8 bf16 (4 VGPRs)
typedef __attribute__((ext_vector_type(4))) float f32x4;   // MFMA C/D

static __device__ __forceinline__ unsigned short f2bf(float f) {
  unsigned int u = __float_as_uint(f);
  u += 0x7fffu + ((u >> 16) & 1u);
  return (unsigned short)(u >> 16);
}
// Block-uniform value -> SGPR (all lanes hold identical bits; lane0's copy).
static __device__ __forceinline__ float rfl(float v) {
  return __builtin_bit_cast(float, __builtin_amdgcn_readfirstlane(__builtin_bit_cast(int, v)));
}
// wave64 max-reduce via DPP, broadcast to all lanes.
static __device__ __forceinline__ float wave_max_f32(float v) {
  float t;
  t = __builtin_bit_cast(float, __builtin_amdgcn_update_dpp(__builtin_bit_cast(int, v), __builtin_bit_cast(int, v), 0x111, 0xF, 0xF, false)); v = fmaxf(v, t); // row_shr:1
  t = __builtin_bit_cast(float, __builtin_amdgcn_update_dpp(__builtin_bit_cast(int, v), __builtin_bit_cast(int, v), 0x112, 0xF, 0xF, false)); v = fmaxf(v, t); // row_shr:2
  t = __builtin_bit_cast(float, __builtin_amdgcn_update_dpp(__builtin_bit_cast(int, v), __builtin_bit_cast(int, v), 0x114, 0xF, 0xF, false)); v = fmaxf(v, t); // row_shr:4
  t = __builtin_bit_cast(float, __builtin_amdgcn_update_dpp(__builtin_bit_cast(int, v), __builtin_bit_cast(int, v), 0x118, 0xF, 0xF, false)); v = fmaxf(v, t); // row_shr:8
  t = __builtin_bit_cast(float, __builtin_amdgcn_update_dpp(__builtin_bit_cast(int, v), __builtin_bit_cast(int, v), 0x142, 0xF, 0xF, false)); v = fmaxf(v, t); // row_bcast:15
  t = __builtin_bit_cast(float, __builtin_amdgcn_update_dpp(__builtin_bit_cast(int, v), __builtin_bit_cast(int, v), 0x143, 0xF, 0xF, false)); v = fmaxf(v, t); // row_bcast:31
  return __builtin_bit_cast(float, __builtin_amdgcn_readlane(__builtin_bit_cast(int, v), 63));
}

// ---------------- prep + Wt bf16 cast (UNCHANGED; proven) ----------------
__global__ __launch_bounds__(256) void k_pre(const float* __restrict__ affines,
                                             const int* __restrict__ prot_mask,
                                             const float* __restrict__ lit,
                                             const float* __restrict__ w,
                                             float* __restrict__ out,
                                             float4* __restrict__ pos4,
                                             float4* __restrict__ ncac4,
                                             unsigned short* __restrict__ wtb) {
  int t = blockIdx.x * 256 + threadIdx.x;  // < 131072
  {  // bf16 cast of ne_weight -> wtb[64][2048] (K-contiguous, zero pad)
    int o = t >> 11, k = t & 2047;
    wtb[t] = (k < 2000) ? f2bf(w[(size_t)o * 2000 + k]) : (unsigned short)0;
  }
  if (t < NNODES) {  // prep: positions, n2, ncac
    int n = t;
    const float4* af = (const float4*)affines + (size_t)n * 3;
    float4 a0 = af[0], a1 = af[1], a2 = af[2];  // rows of rot, .w = trans
    float tx = a0.w, ty = a1.w, tz = a2.w;
    float n2;
    {
#pragma clang fp contract(off)
      float xx = tx * tx;
      float yy = ty * ty;
      float zz = tz * tz;
      n2 = (xx + yy) + zz;
    }
    pos4[n] = make_float4(tx, ty, tz, n2);
    out[O_POS + n * 3 + 0] = tx;
    out[O_POS + n * 3 + 1] = ty;
    out[O_POS + n * 3 + 2] = tz;
    int aat = (prot_mask[n] != 0) ? 0 : 20;
    const float* lp = lit + aat * 9;
#pragma unroll
    for (int a = 0; a < 3; a++) {
      float l0 = lp[a * 3 + 0], l1 = lp[a * 3 + 1], l2 = lp[a * 3 + 2];
      float x = a0.x * l0 + a0.y * l1 + a0.z * l2 + tx;
      float y = a1.x * l0 + a1.y * l1 + a1.z * l2 + ty;
      float z = a2.x * l0 + a2.y * l1 + a2.z * l2 + tz;
      ncac4[n * 3 + a] = make_float4(x, y, z, 0.f);
    }
  }
}

// ---------------- FUSED KNN + gather + MFMA GEMM: QB=16, 1024 threads ----------------
// R10 == R9 with the pragma placement fixed (pragma must open a compound stmt).
// Queries live in SGPRs (readfirstlane of block-uniform loads) -- kills the
// R5-R8 register-spill regression (VGPR demand ~90 at alloc 32/52). Pass 1
// runs TWO half-rounds of 8 queries (32 q-SGPRs live at a time; one extra
// L2-resident pos4 sweep). All arithmetic bit-identical:
//   dot = fmaf(z,pcz, fmaf(y,pcy, x*pcx)); d2 = fmaf(-2,dot,n2q+n2c)
// Partitions: 16 threads x 8 cands = 128 cands (same size as all passing
// rounds); pivot = 21st-smallest of 64 partition minima => exact top-20 via
// u64 (key<<13|idx) rank-select. GEMM: 16 waves = 4 K-quarters x 4 N-quarters,
// intact 16-step MFMA chains, same red[] slots, same s0+s1+s2+s3 reduce ->
// BIT-IDENTICAL output.
__global__ __launch_bounds__(1024, 8) void k_knng(const float4* __restrict__ pos4,
                                                  const float* __restrict__ affines,
                                                  const float4* __restrict__ ncac4,
                                                  const float4* __restrict__ x4,
                                                  const unsigned short* __restrict__ wtb,
                                                  float* __restrict__ out) {
  __shared__ __align__(16) union {
    struct {
      float mca[QB][64];                   //  4 KB group minima
      unsigned long long surv[QB][SCAP];   // 24 KB
      unsigned short jobs[JCAP];           //  8 KB (guarded)
      float dnbuf[QB][KZ];
      int nidx[QB][KZ];
      float pivots[QB];
      unsigned int cnt[QB];
      unsigned int njobs;
    } k;                                    // ~39.6 KB
    unsigned short albs[16][2056];          // 65.8 KB gemm A-tile
    float red[4][16][68];                   // 17.4 KB overlay (after albs dead)
  } u;
  __shared__ float distbuf[QB][100];        // 6.4 KB, persists knng->gemm
  int tid = threadIdx.x;
  int lane = tid & 63, w = tid >> 6;        // w in 0..15
  int qbase = blockIdx.x * QB;
  // x-copy prefetch: 16 rows x 64 float4 = 1024 items, 1 per thread.
  int xr = tid >> 6, xc = tid & 63;
  float4 xv = x4[(size_t)(qbase + xr) * 64 + xc];
  const float4* pp = pos4 + tid;
  float l[QB];
#pragma unroll
  for (int i = 0; i < QB; i++) l[i] = __builtin_inff();
  {  // ---- pass 1: two half-rounds; 8 queries in SGPRs each; 8 cands/thread ----
#pragma unroll
    for (int h = 0; h < 2; h++) {
      float qx[8], qy[8], qz[8], qw[8];  // SGPRs via rfl (block-uniform)
#pragma unroll
      for (int i = 0; i < 8; i++) {
        float4 qq = pos4[qbase + h * 8 + i];
        qx[i] = rfl(qq.x); qy[i] = rfl(qq.y); qz[i] = rfl(qq.z); qw[i] = rfl(qq.w);
      }
      {  // pragma must be first statement of a compound block
#pragma clang fp contract(off)
#pragma unroll 2
        for (int s = 0; s < 8; s++) {
          float4 pc = pp[s << 10];
#pragma unroll
          for (int i = 0; i < 8; i++) {  // each VALU op reads <=1 SGPR (ISA-legal)
            float d = fmaf(-2.0f, fmaf(qz[i], pc.z, fmaf(qy[i], pc.y, qx[i] * pc.x)), qw[i] + pc.w);
            l[h * 8 + i] = fminf(l[h * 8 + i], d);
          }
        }
      }
    }
  }
  {  // ---- group-of-16 minima via shfl_xor(1,2,4,8) -> mca[q][tid>>4] ----
#pragma unroll
    for (int i = 0; i < QB; i++) {
      float v = l[i];
      v = fminf(v, __shfl_xor(v, 1));
      v = fminf(v, __shfl_xor(v, 2));
      v = fminf(v, __shfl_xor(v, 4));
      v = fminf(v, __shfl_xor(v, 8));
      if ((tid & 15) == 0) u.k.mca[i][tid >> 4] = v;
    }
  }
  if (tid == 0) u.k.njobs = 0u;
  __syncthreads();
  {  // ---- pivot: wave w handles query w ----
    float m = u.k.mca[w][lane];
    int c = 0;
#pragma unroll 8
    for (int j = 0; j < 64; j++) c += (u.k.mca[w][j] < m) ? 1 : 0;
    float elig = (c < KZ + 1) ? m : -__builtin_inff();
    float piv = wave_max_f32(elig);
    if (lane == 0) { u.k.pivots[w] = piv; u.k.cnt[w] = 0u; }
  }
  __syncthreads();
  {  // ---- job build: ballot-compacted (1 atomic per wave per query) ----
    unsigned long long lmask = (lane == 63) ? ~0ull : ((1ull << (lane + 1)) - 1ull);
    unsigned long long ltmask = lmask >> 1;  // lanes strictly below me
#pragma unroll
    for (int i = 0; i < QB; i++) {
      float pv = rfl(u.k.pivots[i]);   // block-uniform -> SGPR
      bool p = (l[i] <= pv);
      unsigned long long mask = __ballot(p);
      if (p) {
        int leader = __ffsll((long long)mask) - 1;
        unsigned int base = 0;
        if (lane == leader) base = atomicAdd(&u.k.njobs, (unsigned int)__popcll(mask));
        base = (unsigned int)__shfl((int)base, leader);
        unsigned int ix = base + (unsigned int)__popcll(mask & ltmask);
        if (ix < JCAP) u.k.jobs[ix] = (unsigned short)((i << 10) | tid);
      }
    }
  }
  __syncthreads();
  {  // ---- pass 2 (compacted): each job rescans its owner's 8 cands, 1 query ----
#pragma clang fp contract(off)
    unsigned int nj = u.k.njobs; if (nj > JCAP) nj = JCAP;
    for (unsigned int j = tid; j < nj; j += NTH) {
      int job = u.k.jobs[j];
      int q = job >> 10, owner = job & 1023;
      int qidx = qbase + q;
      float4 qv = pos4[qidx];
      float pv = u.k.pivots[q];
      const float4* src = pos4 + owner;
#pragma unroll
      for (int s = 0; s < 8; s++) {
        float4 pc = src[s << 10];
        float dot = fmaf(qv.z, pc.z, fmaf(qv.y, pc.y, qv.x * pc.x));
        float d2 = fmaf(-2.0f, dot, qv.w + pc.w);
        int cc = (s << 10) + owner;
        if (d2 <= pv && cc != qidx) {
          unsigned int b = __float_as_uint(d2);
          unsigned int k = (b & 0x80000000u) ? ~b : (b | 0x80000000u);
          unsigned int ix = atomicAdd(&u.k.cnt[q], 1u);
          if (ix < SCAP)  // guard (never hit for this data)
            u.k.surv[q][ix] = ((unsigned long long)k << 13) | (unsigned int)cc;
        }
      }
    }
  }
  __syncthreads();
  {  // ---- exact rank-select: wave w handles query w ----
    unsigned int n = u.k.cnt[w]; if (n > SCAP) n = SCAP;
    int qi = qbase + w;
    for (unsigned int j = lane; j < n; j += 64) {
      unsigned long long my = u.k.surv[w][j];
      int rank = 0;
      unsigned int t = 0;
      for (; t + 4 <= n; t += 4) {
        unsigned long long s0 = u.k.surv[w][t + 0];
        unsigned long long s1 = u.k.surv[w][t + 1];
        unsigned long long s2 = u.k.surv[w][t + 2];
        unsigned long long s3 = u.k.surv[w][t + 3];
        rank += ((s0 < my) ? 1 : 0) + ((s1 < my) ? 1 : 0) +
                ((s2 < my) ? 1 : 0) + ((s3 < my) ? 1 : 0);
      }
      for (; t < n; t++) rank += (u.k.surv[w][t] < my) ? 1 : 0;
      if (rank < KZ) {
        int idx = (int)(my & 0x1FFFull);
        u.k.nidx[w][rank] = idx;
        float fi = (float)idx;
        out[O_EDGE + qi * KZ + rank] = fi;                     // edge_index
        out[O_FE + qi * KZ + rank] = fi;                       // full_edge row0
        out[O_FE + NNODES * KZ + qi * KZ + rank] = (float)qi;  // full_edge row1
      }
    }
  }
  // NO block barrier: nidx[w]/dnbuf[w] are wave-private.
  ((float4*)out)[(size_t)(qbase + xr) * 80 + xc] = xv;  // x-copy store
  __builtin_amdgcn_s_waitcnt(0xC07F);  // lgkmcnt(0): my wave's nidx writes visible
  __builtin_amdgcn_wave_barrier();
  {  // ---- gather tail: wave w serves query w on lanes 0..19 ----
    int qi = qbase + w;
    if (lane < KZ) {
      const float4* af = (const float4*)affines + (size_t)qi * 3;
      float4 a0 = af[0], a1 = af[1], a2 = af[2];
      float tx = a0.w, ty = a1.w, tz = a2.w;
      int idx = u.k.nidx[w][lane];
      float4 p = pos4[idx];
      float bx = p.x - tx, by = p.y - ty, bz = p.z - tz;
      // einsum('nji,nkj->nki'): v_i = sum_j rot[j][i]*b_j (rot^T)
      float vx = a0.x * bx + a1.x * by + a2.x * bz;
      float vy = a0.y * bx + a1.y * by + a2.y * bz;
      float vz = a0.z * bx + a1.z * by + a2.z * bz;
      out[O_NBP + qi * 60 + lane * 3 + 0] = vx;
      out[O_NBP + qi * 60 + lane * 3 + 1] = vy;
      out[O_NBP + qi * 60 + lane * 3 + 2] = vz;
      float dn = sqrtf(vx * vx + vy * vy + vz * vz);
      u.k.dnbuf[w][lane] = dn;
      float4 cn = ncac4[(size_t)qi * 3 + 0];   // n_pos
      float4 ca = ncac4[(size_t)qi * 3 + 1];   // ca_pos
      float4 cc = ncac4[(size_t)qi * 3 + 2];   // c_pos
      float4 nb0 = ncac4[(size_t)idx * 3 + 0];
      float4 nb1 = ncac4[(size_t)idx * 3 + 1];
      float4 nb2 = ncac4[(size_t)idx * 3 + 2];
      auto dist = [](float4 a, float4 b) {
        float dx = a.x - b.x, dy = a.y - b.y, dz = a.z - b.z;
        return sqrtf(dx * dx + dy * dy + dz * dz);
      };
      distbuf[w][lane * 3 + 0] = dist(nb0, ca);
      distbuf[w][lane * 3 + 1] = dist(nb1, ca);
      distbuf[w][lane * 3 + 2] = dist(nb2, ca);
      distbuf[w][60 + lane] = dist(nb2, cn);  // n_to_c
      distbuf[w][80 + lane] = dist(nb0, cc);  // c_to_n
    }
  }
  __builtin_amdgcn_s_waitcnt(0xC07F);  // lgkmcnt(0): my wave's dnbuf writes visible
  __builtin_amdgcn_wave_barrier();
  {  // ---- NBD sinusoidal encode: wave-local, query w, 200 items over 64 lanes ----
    int base0 = O_NBD + (qbase + w) * 400;
    for (int uu = lane; uu < KZ * 10; uu += 64) {
      int nb = uu / 10, j = uu - nb * 10;
      float a = u.k.dnbuf[w][nb] * FREQS[j];
      out[base0 + nb * 20 + j] = __sinf(a);
      out[base0 + nb * 20 + 10 + j] = __cosf(a);
    }
  }
  __syncthreads();  // all distbuf writes visible; k-region dead; albs may clobber union
  // ================= GEMM tail (bit-identical) =================
  {  // ---- stage A-tile: 800 (row,colpair) items; 5x uint4 LDS stores each ----
    for (int uu = tid; uu < 800; uu += NTH) {
      int row = uu / 50, cp = uu - row * 50;  // cols 2cp, 2cp+1
      float dA = distbuf[row][2 * cp];
      float dB = distbuf[row][2 * cp + 1];
      unsigned int dw[20];
#pragma unroll
      for (int j = 0; j < 10; j++) {
        float aA = dA * FREQS[j];
        float aB = dB * FREQS[j];
        unsigned short sA = f2bf(__sinf(aA)), cA = f2bf(__cosf(aA));
        unsigned short sB = f2bf(__sinf(aB)), cB = f2bf(__cosf(aB));
        ((unsigned short*)dw)[j] = sA;
        ((unsigned short*)dw)[10 + j] = cA;
        ((unsigned short*)dw)[20 + j] = sB;
        ((unsigned short*)dw)[30 + j] = cB;
      }
      uint4* dst = (uint4*)&u.albs[row][cp * 40];  // 80B, 16B-aligned
#pragma unroll
      for (int v = 0; v < 5; v++)
        dst[v] = ((const uint4*)dw)[v];
    }
    // zero K-pad cols [2000,2048): 6 uint4 per row x 16 rows
    for (int uu = tid; uu < 16 * 6; uu += NTH) {
      int row = uu / 6, v = uu - row * 6;
      ((uint4*)&u.albs[row][2000])[v] = make_uint4(0u, 0u, 0u, 0u);
    }
  }
  __syncthreads();
  int m0 = qbase;
  int kq = w & 3, nq = w >> 2;        // k-quarter, n-quarter (16 waves)
  int am = lane & 15, ak = (lane >> 4) * 8;
  const unsigned short* arow = &u.albs[am][kq * 512 + ak];
  const unsigned short* brow = wtb + (size_t)(am + nq * 16) * 2048 + kq * 512 + ak;
  f32x4 acc = {0.f, 0.f, 0.f, 0.f};
#pragma unroll 8
  for (int ks = 0; ks < 16; ks++) {
    bfrag a = *(const bfrag*)(arow + ks * 32);
    bfrag b = *(const bfrag*)(brow + ks * 32);
    acc = __builtin_amdgcn_mfma_f32_16x16x32_bf16(a, b, acc, 0, 0, 0);
  }
  __syncthreads();  // all albs reads done; red may overlay
  {  // write partials: row=(lane>>4)*4+r_, col=lane&15 (+16 per n-quarter)
    int rm = (lane >> 4) * 4, cn = lane & 15;
#pragma unroll
    for (int r_ = 0; r_ < 4; r_++)
      u.red[kq][rm + r_][nq * 16 + cn] = acc[r_];
  }
  __syncthreads();
  if (tid < 256) {
    // reduce 4 partials; 256 threads x one float4 = 16 rows x 64 cols
    int m = tid >> 4, n = (tid & 15) * 4;
    float4 s0 = *(const float4*)&u.red[0][m][n];
    float4 s1 = *(const float4*)&u.red[1][m][n];
    float4 s2 = *(const float4*)&u.red[2][m][n];
    float4 s3 = *(const float4*)&u.red[3][m][n];
    float4 s = make_float4(s0.x + s1.x + s2.x + s3.x, s0.y + s1.y + s2.y + s3.y,
                           s0.z + s1.z + s2.z + s3.z, s0.w + s1.w + s2.w + s3.w);
    *(float4*)&out[(size_t)(m0 + m) * 320 + 256 + n] = s;
  }
}

extern "C" void kernel_launch(void* const* d_in, const int* in_sizes, int n_in,
                              void* d_out, int out_size, void* d_ws, size_t ws_size,
                              hipStream_t stream) {
  const float* x = (const float*)d_in[0];
  const float* affines = (const float*)d_in[1];
  const float* ne_w = (const float*)d_in[2];
  const float* lit = (const float*)d_in[3];
  const int* mask = (const int*)d_in[4];
  float* out = (float*)d_out;
  char* ws = (char*)d_ws;
  // ws layout (bytes)
  float4* pos4 = (float4*)(ws + 0);                   //  8192*16   = 131072
  float4* ncac4 = (float4*)(ws + 131072);             //  8192*48   -> 524288
  unsigned short* wtb = (unsigned short*)(ws + 524288);   // 64*2048*2 -> 786432

  k_pre<<<512, 256, 0, stream>>>(affines, mask, lit, ne_w, out, pos4, ncac4, wtb);
  k_knng<<<NNODES / QB, NTH, 0, stream>>>(pos4, affines, ncac4, (const float4*)x, wtb, out);
}